// Round 1
// baseline (518.102 us; speedup 1.0000x reference)
//
#include <hip/hip_runtime.h>
#include <hip/hip_fp16.h>

typedef _Float16 h4_t __attribute__((ext_vector_type(4)));
typedef _Float16 h8_t __attribute__((ext_vector_type(8)));
typedef float f4_t __attribute__((ext_vector_type(4)));

#define B_SZ 1024
#define N_IN 512
#define HID 64
#define N_OUT 256
#define QKN (N_OUT * HID) /* 16384 */

// ---------------------------------------------------------------------------
// Kernel 1: LayerNorm(x) -> h (fp16).  One wave per row of 512.
// ---------------------------------------------------------------------------
__global__ __launch_bounds__(256) void k_ln(const float* __restrict__ x,
                                            const float* __restrict__ gamma,
                                            const float* __restrict__ beta,
                                            _Float16* __restrict__ h16) {
    int tid = threadIdx.x;
    int wave = tid >> 6, lane = tid & 63;
    int row = blockIdx.x * 4 + wave;
    const float4* xr = (const float4*)(x + (size_t)row * N_IN);
    float4 a = xr[lane];
    float4 b = xr[lane + 64];
    float s = a.x + a.y + a.z + a.w + b.x + b.y + b.z + b.w;
    float sq = a.x * a.x + a.y * a.y + a.z * a.z + a.w * a.w +
               b.x * b.x + b.y * b.y + b.z * b.z + b.w * b.w;
    for (int off = 1; off < 64; off <<= 1) {
        s += __shfl_xor(s, off);
        sq += __shfl_xor(sq, off);
    }
    float mean = s * (1.0f / N_IN);
    float var = sq * (1.0f / N_IN) - mean * mean;
    float rstd = rsqrtf(var + 1e-5f);
    float4 g0 = ((const float4*)gamma)[lane];
    float4 g1 = ((const float4*)gamma)[lane + 64];
    float4 e0 = ((const float4*)beta)[lane];
    float4 e1 = ((const float4*)beta)[lane + 64];
    h4_t o0 = {(_Float16)((a.x - mean) * rstd * g0.x + e0.x),
               (_Float16)((a.y - mean) * rstd * g0.y + e0.y),
               (_Float16)((a.z - mean) * rstd * g0.z + e0.z),
               (_Float16)((a.w - mean) * rstd * g0.w + e0.w)};
    h4_t o1 = {(_Float16)((b.x - mean) * rstd * g1.x + e1.x),
               (_Float16)((b.y - mean) * rstd * g1.y + e1.y),
               (_Float16)((b.z - mean) * rstd * g1.z + e1.z),
               (_Float16)((b.w - mean) * rstd * g1.w + e1.w)};
    h4_t* hr = (h4_t*)(h16 + (size_t)row * N_IN);
    hr[lane] = o0;
    hr[lane + 64] = o1;
}

// ---------------------------------------------------------------------------
// Kernel 2: Wq/Wk/Wv (512 x 16384 fp32, K-major) -> W^T (16384 x 512 fp16).
// 64x64 tiles via LDS.
// ---------------------------------------------------------------------------
__global__ __launch_bounds__(256) void k_wt(const float* __restrict__ Wq,
                                            const float* __restrict__ Wk,
                                            const float* __restrict__ Wv,
                                            _Float16* __restrict__ wt) {
    __shared__ _Float16 t[64][65];
    const float* W = blockIdx.z == 0 ? Wq : (blockIdx.z == 1 ? Wk : Wv);
    _Float16* out = wt + (size_t)blockIdx.z * ((size_t)QKN * N_IN);
    int n0 = blockIdx.x * 64, k0 = blockIdx.y * 64;
    int c = threadIdx.x & 63, rq = threadIdx.x >> 6;
    for (int i = 0; i < 16; i++) {
        int r = i * 4 + rq;
        t[r][c] = (_Float16)W[(size_t)(k0 + r) * QKN + n0 + c];
    }
    __syncthreads();
    for (int i = 0; i < 16; i++) {
        int r = i * 4 + rq;
        out[(size_t)(n0 + r) * N_IN + k0 + c] = t[c][r];
    }
}

// ---------------------------------------------------------------------------
// Kernel 3: QKV GEMM.  Y = h(1024x512) @ W(512x16384) + b, emitted as fp16.
// m97 structure: 128x128 tile, BK=32, global_load_lds(16B), mfma 16x16x32 f16.
// grid = (8, 128, 3); z selects Wq/Wk/Wv.
// ---------------------------------------------------------------------------
__global__ __launch_bounds__(256) void k_qkv(const _Float16* __restrict__ h16,
                                             const _Float16* __restrict__ wt,
                                             const float* __restrict__ bq,
                                             const float* __restrict__ bk,
                                             const float* __restrict__ bv,
                                             _Float16* __restrict__ qkv) {
    __shared__ _Float16 As[128 * 32];
    __shared__ _Float16 Bs[128 * 32];
    int z = blockIdx.z;
    const _Float16* Wb = wt + (size_t)z * ((size_t)QKN * N_IN);
    const float* bias = z == 0 ? bq : (z == 1 ? bk : bv);
    _Float16* out = qkv + (size_t)z * ((size_t)B_SZ * QKN);
    int m0 = blockIdx.x * 128, n0 = blockIdx.y * 128;
    int tid = threadIdx.x, lane = tid & 63, w = tid >> 6;
    int wm = w & 1, wn = w >> 1;
    int col16 = lane & 15, quad = lane >> 4;
    f4_t acc[4][4] = {};
    for (int kk = 0; kk < N_IN; kk += 32) {
        __syncthreads();
        for (int c = 0; c < 2; c++) {
            int idx = (w * 2 + c) * 512 + lane * 8;
            int row = idx >> 5, col = idx & 31;
            __builtin_amdgcn_global_load_lds(
                (const __attribute__((address_space(1))) void*)(h16 + (size_t)(m0 + row) * N_IN + kk + col),
                (__attribute__((address_space(3))) void*)(As + (w * 2 + c) * 512),
                16, 0, 0);
            __builtin_amdgcn_global_load_lds(
                (const __attribute__((address_space(1))) void*)(Wb + (size_t)(n0 + row) * N_IN + kk + col),
                (__attribute__((address_space(3))) void*)(Bs + (w * 2 + c) * 512),
                16, 0, 0);
        }
        __syncthreads();
        h8_t af[4], bf[4];
        for (int mt = 0; mt < 4; mt++)
            af[mt] = *(const h8_t*)(As + (wm * 64 + mt * 16 + col16) * 32 + quad * 8);
        for (int nt = 0; nt < 4; nt++)
            bf[nt] = *(const h8_t*)(Bs + (wn * 64 + nt * 16 + col16) * 32 + quad * 8);
        for (int mt = 0; mt < 4; mt++)
            for (int nt = 0; nt < 4; nt++)
                acc[mt][nt] = __builtin_amdgcn_mfma_f32_16x16x32_f16(af[mt], bf[nt], acc[mt][nt], 0, 0, 0);
    }
    for (int nt = 0; nt < 4; nt++) {
        int n = n0 + wn * 64 + nt * 16 + col16;
        float bb = bias[n];
        for (int mt = 0; mt < 4; mt++) {
            int mbase = m0 + wm * 64 + mt * 16 + quad * 4;
            for (int r = 0; r < 4; r++)
                out[(size_t)(mbase + r) * QKN + n] = (_Float16)(acc[mt][nt][r] + bb);
        }
    }
}

// ---------------------------------------------------------------------------
// Kernel 4: fused attention + output projection.  One block (4 waves) per
// batch; wave w owns 64 query rows.  S computed TRANSPOSED (K·Q^T) with
// mfma 16x16x16 f16 so the C-layout (row=quad*4+reg) of S^T regs IS the
// B-operand layout of P for P·V, and the C-layout of O IS the A-operand
// layout of `a` for the fused a@Wo.  Zero in-register transposes.
// LDS: [0,16K) halves = K chunked 4-wide (phase1) then Wo^T (phase2);
//      [16K,32K) = V^T chunked 4-wide.  64 KB total, conflict-free frags.
// ---------------------------------------------------------------------------
__global__ __launch_bounds__(256) void k_attn(const _Float16* __restrict__ qkv,
                                              const float* __restrict__ Wo,
                                              const float* __restrict__ bo,
                                              float* __restrict__ out) {
    __shared__ _Float16 lds[32768];
    int b = blockIdx.x;
    int tid = threadIdx.x, lane = tid & 63, w = tid >> 6;
    int col16 = lane & 15, quad = lane >> 4;
    const _Float16* qb = qkv + (size_t)b * QKN;
    const _Float16* kb = qkv + (size_t)(B_SZ + b) * QKN;
    const _Float16* vb = qkv + (size_t)(2 * B_SZ + b) * QKN;

    // stage K -> K4[hid/4][key][4], V -> Vt4[key/4][hid][4]
    {
        int i = tid & 7;       // hid octet
        int kb0 = tid >> 3;    // key 0..31
        for (int it = 0; it < 8; it++) {
            int key = kb0 + it * 32;
            h4_t ka = *(const h4_t*)(kb + key * 64 + i * 8);
            h4_t kc2 = *(const h4_t*)(kb + key * 64 + i * 8 + 4);
            *(h4_t*)(lds + (2 * i) * 1024 + key * 4) = ka;
            *(h4_t*)(lds + (2 * i + 1) * 1024 + key * 4) = kc2;
            const _Float16* vp = vb + key * 64 + i * 8;
            _Float16* vt = lds + 16384 + (key >> 2) * 256 + (key & 3);
            for (int j = 0; j < 8; j++) vt[(i * 8 + j) * 4] = vp[j];
        }
    }
    __syncthreads();

    // Q fragments (B-operand): query = qbase+qt*16+col16, hid = ki*16+quad*4+j
    h4_t qf[4][4];
    int qbase = w * 64;
    for (int qt = 0; qt < 4; qt++)
        for (int ki = 0; ki < 4; ki++)
            qf[qt][ki] = *(const h4_t*)(qb + (qbase + qt * 16 + col16) * 64 + ki * 16 + quad * 4);

    f4_t o[4][4] = {};  // [h-tile][q-tile]
    float mrun[4], lrun[4];
    for (int qt = 0; qt < 4; qt++) { mrun[qt] = -1e30f; lrun[qt] = 0.f; }
    const float sc = 0.125f * 1.44269504088896f;  // scale * log2(e)

    for (int kc = 0; kc < 16; kc++) {
        h4_t kf[4];
        for (int ki = 0; ki < 4; ki++)
            kf[ki] = *(const h4_t*)(lds + (ki * 4 + quad) * 1024 + (kc * 16 + col16) * 4);
        f4_t st[4];
        for (int qt = 0; qt < 4; qt++) {
            f4_t a = {};
            for (int ki = 0; ki < 4; ki++)
                a = __builtin_amdgcn_mfma_f32_16x16x16f16(kf[ki], qf[qt][ki], a, 0, 0, 0);
            st[qt] = a;  // S^T tile: key = quad*4+reg, query = col16
        }
        h4_t vf[4];
        for (int mt = 0; mt < 4; mt++)
            vf[mt] = *(const h4_t*)(lds + 16384 + (kc * 4 + quad) * 256 + (mt * 16 + col16) * 4);
        for (int qt = 0; qt < 4; qt++) {
            float s0 = st[qt][0] * sc, s1 = st[qt][1] * sc;
            float s2 = st[qt][2] * sc, s3 = st[qt][3] * sc;
            float cm = fmaxf(fmaxf(s0, s1), fmaxf(s2, s3));
            cm = fmaxf(cm, __shfl_xor(cm, 16));
            cm = fmaxf(cm, __shfl_xor(cm, 32));
            float mnew = fmaxf(mrun[qt], cm);
            float alpha = exp2f(mrun[qt] - mnew);
            float p0 = exp2f(s0 - mnew), p1 = exp2f(s1 - mnew);
            float p2 = exp2f(s2 - mnew), p3 = exp2f(s3 - mnew);
            float ps = p0 + p1 + p2 + p3;
            ps += __shfl_xor(ps, 16);
            ps += __shfl_xor(ps, 32);
            lrun[qt] = lrun[qt] * alpha + ps;
            mrun[qt] = mnew;
            h4_t pf = {(_Float16)p0, (_Float16)p1, (_Float16)p2, (_Float16)p3};
            for (int mt = 0; mt < 4; mt++) {
                f4_t t = o[mt][qt];
                t[0] *= alpha; t[1] *= alpha; t[2] *= alpha; t[3] *= alpha;
                o[mt][qt] = __builtin_amdgcn_mfma_f32_16x16x16f16(vf[mt], pf, t, 0, 0, 0);
            }
        }
    }

    // normalize; O's C-layout (q=col16, h=quad*4+reg) == A-operand layout of a
    h4_t af[4][4];  // [qt][hk]
    for (int qt = 0; qt < 4; qt++) {
        float rl = 1.0f / lrun[qt];
        for (int hk = 0; hk < 4; hk++) {
            f4_t t = o[hk][qt];
            af[qt][hk] = (h4_t){(_Float16)(t[0] * rl), (_Float16)(t[1] * rl),
                                (_Float16)(t[2] * rl), (_Float16)(t[3] * rl)};
        }
    }
    __syncthreads();
    // stage Wo^T -> Wt4[h/4][no][4] over K4's LDS region
    for (int it = 0; it < 64; it++) {
        int f = it * 256 + tid;
        int hh = f >> 8, no = f & 255;
        lds[(hh >> 2) * 1024 + no * 4 + (hh & 3)] = (_Float16)Wo[f];
    }
    __syncthreads();

    float* outb = out + (size_t)b * (N_OUT * N_OUT);
    for (int nc = 0; nc < 4; nc++) {
        for (int nt = 0; nt < 4; nt++) {
            int no = nc * 64 + nt * 16 + col16;
            h4_t wf[4];
            for (int hk = 0; hk < 4; hk++)
                wf[hk] = *(const h4_t*)(lds + (hk * 4 + quad) * 1024 + no * 4);
            float bb = bo[no];
            for (int qt = 0; qt < 4; qt++) {
                f4_t a = {};
                for (int hk = 0; hk < 4; hk++)
                    a = __builtin_amdgcn_mfma_f32_16x16x16f16(af[qt][hk], wf[hk], a, 0, 0, 0);
                int qrow = qbase + qt * 16 + quad * 4;
                for (int r = 0; r < 4; r++) {
                    float v = a[r] + bb;
                    outb[(size_t)(qrow + r) * N_OUT + no] = (v > 0.f) ? -v : 0.f;
                }
            }
        }
    }
}

// ---------------------------------------------------------------------------
extern "C" void kernel_launch(void* const* d_in, const int* in_sizes, int n_in,
                              void* d_out, int out_size, void* d_ws, size_t ws_size,
                              hipStream_t stream) {
    const float* x = (const float*)d_in[0];
    const float* gamma = (const float*)d_in[1];
    const float* beta = (const float*)d_in[2];
    const float* Wq = (const float*)d_in[3];
    const float* bq = (const float*)d_in[4];
    const float* Wk = (const float*)d_in[5];
    const float* bk = (const float*)d_in[6];
    const float* Wv = (const float*)d_in[7];
    const float* bv = (const float*)d_in[8];
    const float* Wo = (const float*)d_in[9];
    const float* bo = (const float*)d_in[10];
    float* out = (float*)d_out;

    _Float16* h16 = (_Float16*)d_ws;                         // 1 MB
    _Float16* wt16 = h16 + (size_t)B_SZ * N_IN;              // 48 MB
    _Float16* qkv16 = wt16 + (size_t)3 * QKN * N_IN;         // 96 MB

    k_ln<<<dim3(B_SZ / 4), 256, 0, stream>>>(x, gamma, beta, h16);
    k_wt<<<dim3(QKN / 64, N_IN / 64, 3), 256, 0, stream>>>(Wq, Wk, Wv, wt16);
    k_qkv<<<dim3(B_SZ / 128, QKN / 128, 3), 256, 0, stream>>>(h16, wt16, bq, bk, bv, qkv16);
    k_attn<<<dim3(B_SZ), 256, 0, stream>>>(qkv16, Wo, bo, out);
}